// Round 1
// baseline (445.588 us; speedup 1.0000x reference)
//
#include <hip/hip_runtime.h>
#include <stdint.h>

typedef unsigned short u16;
typedef __attribute__((ext_vector_type(4))) float    floatx4;
typedef __attribute__((ext_vector_type(8))) __bf16   bf16x8;
typedef __attribute__((ext_vector_type(4))) unsigned int uintx4;

__device__ inline u16 f2bf(float f) {            // RNE float->bf16
  unsigned int u = __builtin_bit_cast(unsigned int, f);
  u += 0x7fffu + ((u >> 16) & 1u);
  return (u16)(u >> 16);
}

#define GLD16(gsrc, ldst)                                                        \
  __builtin_amdgcn_global_load_lds(                                              \
      (__attribute__((address_space(1))) void*)(gsrc),                           \
      (__attribute__((address_space(3))) void*)(ldst), 16, 0, 0)

// ---------------------------------------------------------------------------
// cast x (fp32) -> bf16, 8 elems/thread
__global__ __launch_bounds__(256) void cast_x_kernel(const float* __restrict__ x,
                                                     u16* __restrict__ xb) {
  long i = ((long)blockIdx.x * 256 + threadIdx.x) * 8;
  floatx4 a = *(const floatx4*)(x + i);
  floatx4 b = *(const floatx4*)(x + i + 4);
  uintx4 o;
  o[0] = (unsigned)f2bf(a[0]) | ((unsigned)f2bf(a[1]) << 16);
  o[1] = (unsigned)f2bf(a[2]) | ((unsigned)f2bf(a[3]) << 16);
  o[2] = (unsigned)f2bf(b[0]) | ((unsigned)f2bf(b[1]) << 16);
  o[3] = (unsigned)f2bf(b[2]) | ((unsigned)f2bf(b[3]) << 16);
  *(uintx4*)(xb + i) = o;
}

// transpose-cast the three 1024x1024 weights: WT[z][n][k] = W_z[k][n]
__global__ __launch_bounds__(256) void transpose_cast_w(const float* __restrict__ Wq,
                                                        const float* __restrict__ Wk,
                                                        const float* __restrict__ Wv,
                                                        u16* __restrict__ WT) {
  __shared__ float tile[32][33];
  const int z = blockIdx.z;
  const float* W = (z == 0) ? Wq : (z == 1) ? Wk : Wv;
  u16* dst = WT + (long)z * 1024 * 1024;
  int bx = blockIdx.x * 32, by = blockIdx.y * 32;
  int tx = threadIdx.x, ty = threadIdx.y;                 // 32 x 8
  for (int i = 0; i < 32; i += 8)
    tile[ty + i][tx] = W[(long)(by + ty + i) * 1024 + bx + tx];
  __syncthreads();
  for (int i = 0; i < 32; i += 8)
    dst[(long)(bx + ty + i) * 1024 + by + tx] = f2bf(tile[tx][ty + i]);
}

// ---------------------------------------------------------------------------
// gemm_bt: C[m][n] = sum_k A[m][k] * Bt[n][k]   (A, Bt bf16, lda=ldb=K)
// MODE 0: C bf16 [M,N] += bias[col]          (q,k projection)
// MODE 1: C bf16 scatter vT[b][m][n&2047] += bias[row]   (v^T projection)
// MODE 2: C bf16 [M,N] * (1/32)              (scores)
// MODE 3: C fp32 [M,N]                       (output)
#define BM 128
#define BN 128
#define BK 64

template <int MODE>
__global__ __launch_bounds__(256, 2)
void gemm_bt(const u16* __restrict__ Aall, const u16* __restrict__ Ball,
             void* __restrict__ Call, const float* __restrict__ bias,
             int M, int N, int K, long aStride, long bStride, long cStride) {
  __shared__ __align__(16) u16 As[BM * BK];
  __shared__ __align__(16) u16 Bs[BN * BK];

  const int z = blockIdx.z;
  const u16* A  = Aall + (long)z * aStride;
  const u16* Bt = Ball + (long)z * bStride;

  const int tid  = threadIdx.x;
  const int m0   = blockIdx.y * BM;
  const int n0   = blockIdx.x * BN;
  const int wave = tid >> 6;
  const int lane = tid & 63;
  const int wm   = (wave & 1) * 64;
  const int wn   = (wave >> 1) * 64;
  const int l15  = lane & 15;
  const int quad = lane >> 4;

  floatx4 acc[4][4];
  floatx4 zero = {0.f, 0.f, 0.f, 0.f};
  for (int i = 0; i < 4; ++i)
    for (int j = 0; j < 4; ++j) acc[i][j] = zero;

  // staging: tile = 1024 16B-chunks; chunk ci -> row r=ci>>3, slot sc=ci&7
  // slot sc holds global chunk c = sc ^ (r&7)  (XOR swizzle: conflict-free ds_read_b128)
  int srow[4], scol[4], sdst[4];
  for (int i = 0; i < 4; ++i) {
    int ci = i * 256 + tid;
    int r = ci >> 3, sc = ci & 7;
    srow[i] = r;
    scol[i] = (sc ^ (r & 7)) * 8;
    sdst[i] = ci * 8;
  }

  for (int kt = 0; kt < K; kt += BK) {
#pragma unroll
    for (int i = 0; i < 4; ++i) {
      GLD16(A  + (long)(m0 + srow[i]) * K + kt + scol[i], As + sdst[i]);
      GLD16(Bt + (long)(n0 + srow[i]) * K + kt + scol[i], Bs + sdst[i]);
    }
    __syncthreads();
#pragma unroll
    for (int ks = 0; ks < 2; ++ks) {
      bf16x8 af[4], bfr[4];
#pragma unroll
      for (int mi = 0; mi < 4; ++mi) {
        int r = wm + mi * 16 + l15;
        int ch = r * 8 + ((ks * 4 + quad) ^ (r & 7));
        af[mi] = *(const bf16x8*)(As + ch * 8);
      }
#pragma unroll
      for (int ni = 0; ni < 4; ++ni) {
        int r = wn + ni * 16 + l15;
        int ch = r * 8 + ((ks * 4 + quad) ^ (r & 7));
        bfr[ni] = *(const bf16x8*)(Bs + ch * 8);
      }
#pragma unroll
      for (int mi = 0; mi < 4; ++mi)
#pragma unroll
        for (int ni = 0; ni < 4; ++ni)
          acc[mi][ni] = __builtin_amdgcn_mfma_f32_16x16x32_bf16(
              af[mi], bfr[ni], acc[mi][ni], 0, 0, 0);
    }
    __syncthreads();
  }

  // epilogue: C/D layout col=lane&15, row=quad*4+reg  [verified m89/m91]
#pragma unroll
  for (int mi = 0; mi < 4; ++mi) {
#pragma unroll
    for (int ni = 0; ni < 4; ++ni) {
      int row = m0 + wm + mi * 16 + quad * 4;
      int col = n0 + wn + ni * 16 + l15;
      floatx4 v = acc[mi][ni];
      if (MODE == 0) {
        u16* C = (u16*)Call;
        float b = bias[col];
#pragma unroll
        for (int r = 0; r < 4; ++r)
          C[(long)(row + r) * N + col] = f2bf(v[r] + b);
      } else if (MODE == 1) {
        u16* C = (u16*)Call;                      // vT[b][do][t]: row=do, col=t_global
        long base = ((long)(col >> 11) * 1024) * 2048 + (col & 2047);
#pragma unroll
        for (int r = 0; r < 4; ++r)
          C[base + (long)(row + r) * 2048] = f2bf(v[r] + bias[row + r]);
      } else if (MODE == 2) {
        u16* C = (u16*)Call + (long)z * cStride;
#pragma unroll
        for (int r = 0; r < 4; ++r)
          C[(long)(row + r) * N + col] = f2bf(v[r] * 0.03125f);
      } else {
        float* C = (float*)Call + (long)z * cStride;
#pragma unroll
        for (int r = 0; r < 4; ++r)
          C[(long)(row + r) * N + col] = v[r];
      }
    }
  }
}

// ---------------------------------------------------------------------------
// in-place row softmax over 2048 bf16 (one block per row)
__global__ __launch_bounds__(256) void softmax_rows(u16* __restrict__ S) {
  const long row = blockIdx.x;
  u16* p = S + row * 2048;
  const int tid = threadIdx.x, wave = tid >> 6, lane = tid & 63;
  uintx4 raw = *((const uintx4*)p + tid);
  float v[8];
#pragma unroll
  for (int i = 0; i < 4; ++i) {
    v[2 * i]     = __builtin_bit_cast(float, raw[i] << 16);
    v[2 * i + 1] = __builtin_bit_cast(float, raw[i] & 0xffff0000u);
  }
  float m = v[0];
#pragma unroll
  for (int i = 1; i < 8; ++i) m = fmaxf(m, v[i]);
  for (int off = 32; off > 0; off >>= 1) m = fmaxf(m, __shfl_xor(m, off));
  __shared__ float redm[4], reds[4];
  if (lane == 0) redm[wave] = m;
  __syncthreads();
  m = fmaxf(fmaxf(redm[0], redm[1]), fmaxf(redm[2], redm[3]));
  float e[8], s = 0.f;
#pragma unroll
  for (int i = 0; i < 8; ++i) { e[i] = __expf(v[i] - m); s += e[i]; }
  for (int off = 32; off > 0; off >>= 1) s += __shfl_xor(s, off);
  if (lane == 0) reds[wave] = s;
  __syncthreads();
  s = reds[0] + reds[1] + reds[2] + reds[3];
  float inv = 1.0f / s;
  uintx4 o;
#pragma unroll
  for (int i = 0; i < 4; ++i)
    o[i] = (unsigned)f2bf(e[2 * i] * inv) | ((unsigned)f2bf(e[2 * i + 1] * inv) << 16);
  *((uintx4*)p + tid) = o;
}

// ---------------------------------------------------------------------------
extern "C" void kernel_launch(void* const* d_in, const int* in_sizes, int n_in,
                              void* d_out, int out_size, void* d_ws, size_t ws_size,
                              hipStream_t stream) {
  const float* x  = (const float*)d_in[0];
  const float* Wq = (const float*)d_in[1];
  const float* bq = (const float*)d_in[2];
  const float* Wk = (const float*)d_in[3];
  const float* bk = (const float*)d_in[4];
  const float* Wv = (const float*)d_in[5];
  const float* bv = (const float*)d_in[6];
  float* out = (float*)d_out;

  const long BT = 16384;   // B*T
  u16* xb = (u16*)d_ws;                    // [16384,1024] bf16   32 MB
  u16* WT = xb + BT * 1024;                // [3][1024,1024]       6 MB
  u16* qb = WT + 3L * 1024 * 1024;         // [16384,1024]        32 MB
  u16* kb = qb + BT * 1024;                // [16384,1024]        32 MB
  u16* vT = kb + BT * 1024;                // [8][1024][2048]     32 MB
  u16* S  = vT + BT * 1024;                // [8][2048][2048]     64 MB  (tot ~198 MB)

  cast_x_kernel<<<8192, 256, 0, stream>>>(x, xb);
  transpose_cast_w<<<dim3(32, 32, 3), dim3(32, 8), 0, stream>>>(Wq, Wk, Wv, WT);

  // q = x Wq + bq ; k = x Wk + bk
  gemm_bt<0><<<dim3(8, 128, 1), 256, 0, stream>>>(xb, WT, qb, bq,
                                                  16384, 1024, 1024, 0, 0, 0);
  gemm_bt<0><<<dim3(8, 128, 1), 256, 0, stream>>>(xb, WT + 1024L * 1024, kb, bk,
                                                  16384, 1024, 1024, 0, 0, 0);
  // vT[b][do][t] = (Wv^T x^T + bv) : A=WvT [1024,1024], Bt=xb [16384,1024]
  gemm_bt<1><<<dim3(128, 8, 1), 256, 0, stream>>>(WT + 2L * 1024 * 1024, xb, vT, bv,
                                                  1024, 16384, 1024, 0, 0, 0);
  // S[b] = q_b k_b^T / 32
  gemm_bt<2><<<dim3(16, 16, 8), 256, 0, stream>>>(qb, kb, S, nullptr,
                                                  2048, 2048, 1024,
                                                  2048L * 1024, 2048L * 1024, 2048L * 2048);
  softmax_rows<<<16384, 256, 0, stream>>>(S);
  // out[b] = P_b V_b : A=P [2048,2048], Bt=vT_b [1024,2048]
  gemm_bt<3><<<dim3(8, 16, 8), 256, 0, stream>>>(S, vT, out, nullptr,
                                                 2048, 1024, 2048,
                                                 2048L * 2048, 1024L * 2048, 2048L * 1024);
}

// Round 2
// 427.457 us; speedup vs baseline: 1.0424x; 1.0424x over previous
//
#include <hip/hip_runtime.h>
#include <stdint.h>

typedef unsigned short u16;
typedef __attribute__((ext_vector_type(4))) float    floatx4;
typedef __attribute__((ext_vector_type(8))) __bf16   bf16x8;
typedef __attribute__((ext_vector_type(4))) unsigned int uintx4;

__device__ inline u16 f2bf(float f) {            // RNE float->bf16
  unsigned int u = __builtin_bit_cast(unsigned int, f);
  u += 0x7fffu + ((u >> 16) & 1u);
  return (u16)(u >> 16);
}

#define GLD16(gsrc, ldst)                                                        \
  __builtin_amdgcn_global_load_lds(                                              \
      (__attribute__((address_space(1))) void*)(gsrc),                           \
      (__attribute__((address_space(3))) void*)(ldst), 16, 0, 0)

// ---------------------------------------------------------------------------
// cast x (fp32) -> bf16, 8 elems/thread
__global__ __launch_bounds__(256) void cast_x_kernel(const float* __restrict__ x,
                                                     u16* __restrict__ xb) {
  long i = ((long)blockIdx.x * 256 + threadIdx.x) * 8;
  floatx4 a = *(const floatx4*)(x + i);
  floatx4 b = *(const floatx4*)(x + i + 4);
  uintx4 o;
  o[0] = (unsigned)f2bf(a[0]) | ((unsigned)f2bf(a[1]) << 16);
  o[1] = (unsigned)f2bf(a[2]) | ((unsigned)f2bf(a[3]) << 16);
  o[2] = (unsigned)f2bf(b[0]) | ((unsigned)f2bf(b[1]) << 16);
  o[3] = (unsigned)f2bf(b[2]) | ((unsigned)f2bf(b[3]) << 16);
  *(uintx4*)(xb + i) = o;
}

// transpose-cast the three 1024x1024 weights: WT[z][n][k] = W_z[k][n]
__global__ __launch_bounds__(256) void transpose_cast_w(const float* __restrict__ Wq,
                                                        const float* __restrict__ Wk,
                                                        const float* __restrict__ Wv,
                                                        u16* __restrict__ WT) {
  __shared__ float tile[32][33];
  const int z = blockIdx.z;
  const float* W = (z == 0) ? Wq : (z == 1) ? Wk : Wv;
  u16* dst = WT + (long)z * 1024 * 1024;
  int bx = blockIdx.x * 32, by = blockIdx.y * 32;
  int tx = threadIdx.x, ty = threadIdx.y;                 // 32 x 8
  for (int i = 0; i < 32; i += 8)
    tile[ty + i][tx] = W[(long)(by + ty + i) * 1024 + bx + tx];
  __syncthreads();
  for (int i = 0; i < 32; i += 8)
    dst[(long)(bx + ty + i) * 1024 + by + tx] = f2bf(tile[tx][ty + i]);
}

// ---------------------------------------------------------------------------
// gemm_bt: C[m][n] = sum_k A[m][k] * Bt[n][k]   (A, Bt bf16, lda=ldb=K)
// MODE 0: merged q|k projection: col<1024 -> qb (+bq), else kb (+bk); ldc=1024
// MODE 1: C bf16 scatter vT[b][m][n&2047] += bias[row]   (v^T projection)
// MODE 2: E = exp(s/32) bf16 [M,N]; atomic row-sums into lsum  (scores)
// MODE 3: C fp32 [M,N] = acc / lsum[row]       (output)
#define BM 128
#define BN 128
#define BK 64

template <int MODE, int GN>
__global__ __launch_bounds__(256, 2)
void gemm_bt(const u16* __restrict__ Aall, const u16* __restrict__ Ball,
             void* __restrict__ Call, void* __restrict__ C2,
             const float* __restrict__ bias, const float* __restrict__ bias2,
             float* __restrict__ lsum,
             int M, int N, int K, long aStride, long bStride, long cStride) {
  __shared__ __align__(16) u16 As[BM * BK];
  __shared__ __align__(16) u16 Bs[BN * BK];

  const int z = blockIdx.z;
  const u16* A  = Aall + (long)z * aStride;
  const u16* Bt = Ball + (long)z * bStride;

  // L2-locality swizzle: consecutive ids sweep all m-tiles for a GN-wide n-group
  int m_idx, n_idx;
  if (GN > 0) {
    const int tiles_n = gridDim.x, tiles_m = gridDim.y;
    int bid = blockIdx.y * tiles_n + blockIdx.x;
    int per_group = GN * tiles_m;
    int g = bid / per_group;
    int rem = bid - g * per_group;
    n_idx = g * GN + rem % GN;
    m_idx = rem / GN;
  } else {
    m_idx = blockIdx.y; n_idx = blockIdx.x;
  }

  const int tid  = threadIdx.x;
  const int m0   = m_idx * BM;
  const int n0   = n_idx * BN;
  const int wave = tid >> 6;
  const int lane = tid & 63;
  const int wm   = (wave & 1) * 64;
  const int wn   = (wave >> 1) * 64;
  const int l15  = lane & 15;
  const int quad = lane >> 4;

  floatx4 acc[4][4];
  floatx4 zero = {0.f, 0.f, 0.f, 0.f};
  for (int i = 0; i < 4; ++i)
    for (int j = 0; j < 4; ++j) acc[i][j] = zero;

  // staging: tile = 1024 16B-chunks; chunk ci -> row r=ci>>3, slot sc=ci&7
  // slot sc holds global chunk c = sc ^ (r&7)  (XOR swizzle: conflict-free ds_read_b128)
  int srow[4], scol[4], sdst[4];
  for (int i = 0; i < 4; ++i) {
    int ci = i * 256 + tid;
    int r = ci >> 3, sc = ci & 7;
    srow[i] = r;
    scol[i] = (sc ^ (r & 7)) * 8;
    sdst[i] = ci * 8;
  }

  for (int kt = 0; kt < K; kt += BK) {
#pragma unroll
    for (int i = 0; i < 4; ++i) {
      GLD16(A  + (long)(m0 + srow[i]) * K + kt + scol[i], As + sdst[i]);
      GLD16(Bt + (long)(n0 + srow[i]) * K + kt + scol[i], Bs + sdst[i]);
    }
    __syncthreads();
#pragma unroll
    for (int ks = 0; ks < 2; ++ks) {
      bf16x8 af[4], bfr[4];
#pragma unroll
      for (int mi = 0; mi < 4; ++mi) {
        int r = wm + mi * 16 + l15;
        int ch = r * 8 + ((ks * 4 + quad) ^ (r & 7));
        af[mi] = *(const bf16x8*)(As + ch * 8);
      }
#pragma unroll
      for (int ni = 0; ni < 4; ++ni) {
        int r = wn + ni * 16 + l15;
        int ch = r * 8 + ((ks * 4 + quad) ^ (r & 7));
        bfr[ni] = *(const bf16x8*)(Bs + ch * 8);
      }
#pragma unroll
      for (int mi = 0; mi < 4; ++mi)
#pragma unroll
        for (int ni = 0; ni < 4; ++ni)
          acc[mi][ni] = __builtin_amdgcn_mfma_f32_16x16x32_bf16(
              af[mi], bfr[ni], acc[mi][ni], 0, 0, 0);
    }
    __syncthreads();
  }

  // epilogue: C/D layout col=lane&15, row=quad*4+reg  [verified m89/m91]
#pragma unroll
  for (int mi = 0; mi < 4; ++mi) {
    const int row = m0 + wm + mi * 16 + quad * 4;
    if (MODE == 2) {
      u16* C = (u16*)Call + (long)z * cStride;
      float rs[4] = {0.f, 0.f, 0.f, 0.f};
#pragma unroll
      for (int ni = 0; ni < 4; ++ni) {
        int col = n0 + wn + ni * 16 + l15;
        floatx4 v = acc[mi][ni];
#pragma unroll
        for (int r = 0; r < 4; ++r) {
          float e = __expf(v[r] * 0.03125f);
          C[(long)(row + r) * N + col] = f2bf(e);
          rs[r] += e;
        }
      }
#pragma unroll
      for (int r = 0; r < 4; ++r) {
        float t = rs[r];
        t += __shfl_xor(t, 1);
        t += __shfl_xor(t, 2);
        t += __shfl_xor(t, 4);
        t += __shfl_xor(t, 8);
        if (l15 == 0) atomicAdd(lsum + (long)z * 2048 + row + r, t);
      }
    } else if (MODE == 3) {
      float* C = (float*)Call + (long)z * cStride;
      const float* lz = lsum + (long)z * 2048;
      floatx4 lv = *(const floatx4*)(lz + row);
      float inv[4];
#pragma unroll
      for (int r = 0; r < 4; ++r) inv[r] = 1.0f / lv[r];
#pragma unroll
      for (int ni = 0; ni < 4; ++ni) {
        int col = n0 + wn + ni * 16 + l15;
        floatx4 v = acc[mi][ni];
#pragma unroll
        for (int r = 0; r < 4; ++r)
          C[(long)(row + r) * N + col] = v[r] * inv[r];
      }
    } else if (MODE == 0) {
#pragma unroll
      for (int ni = 0; ni < 4; ++ni) {
        int col = n0 + wn + ni * 16 + l15;
        u16* C = (col < 1024) ? (u16*)Call : (u16*)C2;
        float b = (col < 1024) ? bias[col] : bias2[col - 1024];
        int c = col & 1023;
        floatx4 v = acc[mi][ni];
#pragma unroll
        for (int r = 0; r < 4; ++r)
          C[(long)(row + r) * 1024 + c] = f2bf(v[r] + b);
      }
    } else {  // MODE 1: vT scatter
      u16* C = (u16*)Call;
#pragma unroll
      for (int ni = 0; ni < 4; ++ni) {
        int col = n0 + wn + ni * 16 + l15;    // global t index over B*T
        long base = ((long)(col >> 11) * 1024) * 2048 + (col & 2047);
        floatx4 v = acc[mi][ni];
#pragma unroll
        for (int r = 0; r < 4; ++r)
          C[base + (long)(row + r) * 2048] = f2bf(v[r] + bias[row + r]);
      }
    }
  }
}

// ---------------------------------------------------------------------------
extern "C" void kernel_launch(void* const* d_in, const int* in_sizes, int n_in,
                              void* d_out, int out_size, void* d_ws, size_t ws_size,
                              hipStream_t stream) {
  const float* x  = (const float*)d_in[0];
  const float* Wq = (const float*)d_in[1];
  const float* bq = (const float*)d_in[2];
  const float* Wk = (const float*)d_in[3];
  const float* bk = (const float*)d_in[4];
  const float* Wv = (const float*)d_in[5];
  const float* bv = (const float*)d_in[6];
  float* out = (float*)d_out;

  const long BT = 16384;   // B*T
  u16* xb = (u16*)d_ws;                    // [16384,1024] bf16   32 MB
  u16* WT = xb + BT * 1024;                // [3][1024,1024]       6 MB
  u16* qb = WT + 3L * 1024 * 1024;         // [16384,1024]        32 MB
  u16* kb = qb + BT * 1024;                // [16384,1024]        32 MB
  u16* vT = kb + BT * 1024;                // [8][1024][2048]     32 MB
  u16* S  = vT + BT * 1024;                // [8][2048][2048]     64 MB
  float* lsum = (float*)(S + 8L * 2048 * 2048);   // [8][2048]    64 KB

  hipMemsetAsync(lsum, 0, 8 * 2048 * sizeof(float), stream);

  cast_x_kernel<<<8192, 256, 0, stream>>>(x, xb);
  transpose_cast_w<<<dim3(32, 32, 3), dim3(32, 8), 0, stream>>>(Wq, Wk, Wv, WT);

  // q|k = x [Wq|Wk] + [bq|bk]   (WT rows 0..2047 are Wq^T then Wk^T)
  gemm_bt<0, 8><<<dim3(16, 128, 1), 256, 0, stream>>>(
      xb, WT, qb, kb, bq, bk, nullptr, 16384, 2048, 1024, 0, 0, 0);
  // vT[b][do][t] = (Wv^T x^T + bv) : A=WvT [1024,1024], Bt=xb [16384,1024]
  gemm_bt<1, 8><<<dim3(128, 8, 1), 256, 0, stream>>>(
      WT + 2L * 1024 * 1024, xb, vT, nullptr, bv, nullptr, nullptr,
      1024, 16384, 1024, 0, 0, 0);
  // E[b] = exp(q_b k_b^T / 32), row-sums -> lsum
  gemm_bt<2, 8><<<dim3(16, 16, 8), 256, 0, stream>>>(
      qb, kb, S, nullptr, nullptr, nullptr, lsum,
      2048, 2048, 1024, 2048L * 1024, 2048L * 1024, 2048L * 2048);
  // out[b] = (E_b V_b) / lsum : A=E [2048,2048], Bt=vT_b [1024,2048]
  gemm_bt<3, 8><<<dim3(8, 16, 8), 256, 0, stream>>>(
      S, vT, out, nullptr, nullptr, nullptr, lsum,
      2048, 1024, 2048, 2048L * 2048, 1024L * 2048, 2048L * 1024);
}